// Round 5
// baseline (3471.918 us; speedup 1.0000x reference)
//
#include <hip/hip_runtime.h>
#include <math.h>

#define B 128
#define L 2048
#define H 512
#define D 512
#define NG 2048   // 4*H
#define T 10
#define S 16      // L-chunks per batch row for attention partials
#define GB 256    // gates blocks fused in front of attention blocks

// workspace layout (float offsets); ws_size = 2 GiB
#define OFF_S    ((size_t)0)        // c state (attention query), B*H
#define OFF_H    ((size_t)65536)    // hidden h, B*H
#define OFF_X    ((size_t)131072)   // current x, B*D
#define OFF_SS   ((size_t)196608)   // ||s||^2 per b, B
#define OFF_G    ((size_t)196736)   // gates, B*NG
#define OFF_PL   ((size_t)460928)   // partial l, B*S
#define OFF_PCTX ((size_t)462976)   // partial ctx, B*S*H
#define OFF_RN   ((size_t)1511552)  // 1/||h_l||, B*L
#define OFF_HB   ((size_t)1773696)  // bf16 copy of hid_states (row-major), B*L*H bf16

__device__ __forceinline__ float sigf(float x){ return 1.0f / (1.0f + __expf(-x)); }

__device__ __forceinline__ unsigned int b16r(float f){   // fp32 -> bf16 bits, RNE
    unsigned int u = __float_as_uint(f);
    return (u + 0x7FFFu + ((u >> 16) & 1u)) >> 16;
}
__device__ __forceinline__ unsigned int pack2(float lo, float hi){
    return b16r(lo) | (b16r(hi) << 16);
}

#define UNPK(u, f0, f1) { f0 = __uint_as_float((u) << 16); f1 = __uint_as_float((u) & 0xFFFF0000u); }

// reduce over the 32-lane half-wave (xor 1..16 stays within each half)
__device__ __forceinline__ float red32(float v){
    v += __shfl_xor(v, 1, 64);
    v += __shfl_xor(v, 2, 64);
    v += __shfl_xor(v, 4, 64);
    v += __shfl_xor(v, 8, 64);
    v += __shfl_xor(v, 16, 64);
    return v;
}

__device__ __forceinline__ float block_sum256s(float v, float* r4){
    for (int off = 32; off; off >>= 1) v += __shfl_xor(v, off, 64);
    int wave = threadIdx.x >> 6, lane = threadIdx.x & 63;
    if (lane == 0) r4[wave] = v;
    __syncthreads();
    return r4[0] + r4[1] + r4[2] + r4[3];
}

// ---- load s (pre-scaled by 1/||s||) into 16 regs: elements g2*16 .. +15 ----
__device__ __forceinline__ void load_snorm16(const float* sptr, float rssb, int g2, float* sf){
    const float* sb = sptr + g2 * 16;
    #pragma unroll
    for (int q = 0; q < 4; q++){
        float4 a = *(const float4*)(sb + q*4);
        sf[q*4+0] = a.x * rssb; sf[q*4+1] = a.y * rssb;
        sf[q*4+2] = a.z * rssb; sf[q*4+3] = a.w * rssb;
    }
}

// ---- epilogue: combine halves + waves, write chunk partials ----
__device__ __forceinline__ void attn_epilogue32(float* ctx, float lsum, float* smem,
                                                float* __restrict__ pl, float* __restrict__ pc,
                                                int wave, int g2, int lane){
    #pragma unroll
    for (int k = 0; k < 16; k++) ctx[k] += __shfl_xor(ctx[k], 32, 64);
    lsum += __shfl_xor(lsum, 32, 64);

    float (*lctx)[512] = (float(*)[512])smem;   // 4*512 floats
    float* ll = smem + 2048;                    // 4 floats
    if (lane < 32){
        #pragma unroll
        for (int q = 0; q < 4; q++){
            float4 v = { ctx[q*4+0], ctx[q*4+1], ctx[q*4+2], ctx[q*4+3] };
            *(float4*)&lctx[wave][g2*16 + q*4] = v;
        }
        if (g2 == 0) ll[wave] = lsum;
    }
    __syncthreads();
    int t = threadIdx.x;
    pc[t]       = lctx[0][t]     + lctx[1][t]     + lctx[2][t]     + lctx[3][t];
    pc[t + 256] = lctx[0][t+256] + lctx[1][t+256] + lctx[2][t+256] + lctx[3][t+256];
    if (t == 0) pl[0] = ll[0] + ll[1] + ll[2] + ll[3];
}

// ---- step-0 attention: reads fp32 hid, emits row-major bf16 copy + rn ----
// 32 lanes x 16 elems; 2 rows/iter (r2 parity), 16 iterations per wave (32 rows)
__device__ __forceinline__ void attn_first_body(const float* __restrict__ hid,
                                                const float* __restrict__ sptr, float rssb,
                                                float* __restrict__ ws, float* smem,
                                                float* __restrict__ pl, float* __restrict__ pc,
                                                int b, int chunk){
    int wave = threadIdx.x >> 6, lane = threadIdx.x & 63;
    int g2 = lane & 31, r2 = lane >> 5;
    float sf[16];
    load_snorm16(sptr, rssb, g2, sf);

    int l0w = chunk * 128 + wave * 32;
    const float* hsrc = hid + ((size_t)b * L + l0w) * H + g2 * 16;
    uint4* hbw = (uint4*)(ws + OFF_HB) + ((size_t)b * L + l0w) * 64 + g2 * 2;
    float* rnw = ws + OFF_RN + (size_t)b * L + l0w;

    float ctx[16];
    #pragma unroll
    for (int k = 0; k < 16; k++) ctx[k] = 0.f;
    float lsum = 0.f;

    // prefetch it=0 row
    const float* s0p = hsrc + (size_t)r2 * H;
    float4 x0 = *(const float4*)(s0p);
    float4 x1 = *(const float4*)(s0p + 4);
    float4 x2 = *(const float4*)(s0p + 8);
    float4 x3 = *(const float4*)(s0p + 12);

    #pragma unroll
    for (int it = 0; it < 16; it++){
        int ro = it*2 + r2;
        float4 y0, y1, y2, y3;
        if (it < 15){
            const float* sn = hsrc + (size_t)(ro + 2) * H;
            y0 = *(const float4*)(sn);
            y1 = *(const float4*)(sn + 4);
            y2 = *(const float4*)(sn + 8);
            y3 = *(const float4*)(sn + 12);
        }
        float f[16];
        f[0]=x0.x;  f[1]=x0.y;  f[2]=x0.z;  f[3]=x0.w;
        f[4]=x1.x;  f[5]=x1.y;  f[6]=x1.z;  f[7]=x1.w;
        f[8]=x2.x;  f[9]=x2.y;  f[10]=x2.z; f[11]=x2.w;
        f[12]=x3.x; f[13]=x3.y; f[14]=x3.z; f[15]=x3.w;

        float s0_=0.f, s1_=0.f, d0=0.f, d1=0.f, d2=0.f, d3=0.f;
        #pragma unroll
        for (int k = 0; k < 4; k++){
            s0_ += f[k]*f[k] + f[4+k]*f[4+k];
            s1_ += f[8+k]*f[8+k] + f[12+k]*f[12+k];
            d0 += f[k]*sf[k];
            d1 += f[4+k]*sf[4+k];
            d2 += f[8+k]*sf[8+k];
            d3 += f[12+k]*sf[12+k];
        }
        float sq  = red32(s0_ + s1_);
        float dot = red32((d0 + d1) + (d2 + d3));
        float rnv = rsqrtf(sq);
        if (g2 == 0) rnw[ro] = rnv;

        uint4 o0, o1;
        o0.x = pack2(f[0], f[1]);   o0.y = pack2(f[2], f[3]);
        o0.z = pack2(f[4], f[5]);   o0.w = pack2(f[6], f[7]);
        o1.x = pack2(f[8], f[9]);   o1.y = pack2(f[10], f[11]);
        o1.z = pack2(f[12], f[13]); o1.w = pack2(f[14], f[15]);
        hbw[(size_t)ro * 64]     = o0;
        hbw[(size_t)ro * 64 + 1] = o1;

        float p = __expf(dot * rnv);   // cosine score in [-1,1] -> no max needed
        lsum += p;
        #pragma unroll
        for (int k = 0; k < 16; k++) ctx[k] += p * f[k];

        if (it < 15){ x0 = y0; x1 = y1; x2 = y2; x3 = y3; }
    }
    attn_epilogue32(ctx, lsum, smem, pl, pc, wave, g2, lane);
}

// ---- steady-state attention on row-major bf16 copy; same 32x16 tiling ----
__device__ __forceinline__ void attn_steady_body(const float* __restrict__ sptr, float rssb,
                                                 const float* __restrict__ ws_c, float* smem,
                                                 float* __restrict__ pl, float* __restrict__ pc,
                                                 int b, int chunk){
    int wave = threadIdx.x >> 6, lane = threadIdx.x & 63;
    int g2 = lane & 31, r2 = lane >> 5;
    float sf[16];
    load_snorm16(sptr, rssb, g2, sf);

    int l0w = chunk * 128 + wave * 32;
    const uint4* hbu = (const uint4*)(ws_c + OFF_HB) + ((size_t)b * L + l0w) * 64 + g2 * 2;
    const float* rnp = ws_c + OFF_RN + (size_t)b * L + l0w;

    float ctx[16];
    #pragma unroll
    for (int k = 0; k < 16; k++) ctx[k] = 0.f;
    float lsum = 0.f;

    uint4 ua = hbu[(size_t)r2 * 64];
    uint4 ub = hbu[(size_t)r2 * 64 + 1];
    float rnv = rnp[r2];

    #pragma unroll
    for (int it = 0; it < 16; it++){
        uint4 na, nb; float rnn;
        if (it < 15){
            const uint4* hn = hbu + (size_t)(it*2 + 2 + r2) * 64;
            na = hn[0]; nb = hn[1];
            rnn = rnp[it*2 + 2 + r2];
        }
        float f[16];
        UNPK(ua.x, f[0],  f[1])   UNPK(ua.y, f[2],  f[3])
        UNPK(ua.z, f[4],  f[5])   UNPK(ua.w, f[6],  f[7])
        UNPK(ub.x, f[8],  f[9])   UNPK(ub.y, f[10], f[11])
        UNPK(ub.z, f[12], f[13])  UNPK(ub.w, f[14], f[15])

        float d0=0.f, d1=0.f, d2=0.f, d3=0.f;
        #pragma unroll
        for (int k = 0; k < 4; k++){
            d0 += f[k]*sf[k];
            d1 += f[4+k]*sf[4+k];
            d2 += f[8+k]*sf[8+k];
            d3 += f[12+k]*sf[12+k];
        }
        float dot = red32((d0 + d1) + (d2 + d3));
        float p = __expf(dot * rnv);
        lsum += p;
        #pragma unroll
        for (int k = 0; k < 16; k++) ctx[k] += p * f[k];

        if (it < 15){ ua = na; ub = nb; rnv = rnn; }
    }
    attn_epilogue32(ctx, lsum, smem, pl, pc, wave, g2, lane);
}

// ---- gates = x @ W_ih + h @ W_hh + b ; outer-product, each weight read ONCE per block ----
__device__ __forceinline__ void gates_body(const float* __restrict__ Wih,
                                           const float* __restrict__ Whh,
                                           const float* __restrict__ bias,
                                           const float* __restrict__ xp,
                                           const float* __restrict__ hp,
                                           float* __restrict__ ws,
                                           float* smem, int gid){
    int tid = threadIdx.x;
    int b0 = (gid >> 4) * 8, n0 = (gid & 15) * 128;
    float* xs  = smem;          // [8][512]
    float* hsm = smem + 4096;   // [8][512]
    {
        int r = tid >> 5, c = (tid & 31) * 16;
        const float* xsrc = xp + (size_t)(b0 + r) * D + c;
        const float* hsrc = hp + (size_t)(b0 + r) * H + c;
        #pragma unroll
        for (int j = 0; j < 4; j++){
            *(float4*)&xs[r*512 + c + j*4]  = *(const float4*)(xsrc + j*4);
            *(float4*)&hsm[r*512 + c + j*4] = *(const float4*)(hsrc + j*4);
        }
    }
    __syncthreads();
    int nt = tid & 31, kh = tid >> 5;
    int n = n0 + nt * 4;
    float4 acc[8];
    #pragma unroll
    for (int bi = 0; bi < 8; bi++){ acc[bi].x = 0.f; acc[bi].y = 0.f; acc[bi].z = 0.f; acc[bi].w = 0.f; }
    const float* w1p = Wih + (size_t)(kh * 64) * NG + n;
    const float* w2p = Whh + (size_t)(kh * 64) * NG + n;
    const float* xk = xs  + kh * 64;
    const float* hk = hsm + kh * 64;
    #pragma unroll 2
    for (int k = 0; k < 64; k++){
        float4 w1 = *(const float4*)(w1p + (size_t)k * NG);
        float4 w2 = *(const float4*)(w2p + (size_t)k * NG);
        #pragma unroll
        for (int bi = 0; bi < 8; bi++){
            float xv = xk[bi*512 + k], hv = hk[bi*512 + k];
            acc[bi].x += xv*w1.x + hv*w2.x;
            acc[bi].y += xv*w1.y + hv*w2.y;
            acc[bi].z += xv*w1.z + hv*w2.z;
            acc[bi].w += xv*w1.w + hv*w2.w;
        }
    }
    __syncthreads();                         // all LDS reads done before realias
    float4* red = (float4*)smem;             // [8 kh][8 bi][32 nt] = 8192 floats
    #pragma unroll
    for (int bi = 0; bi < 8; bi++) red[(kh*8 + bi)*32 + nt] = acc[bi];
    __syncthreads();
    int bi2 = tid >> 5, nt2 = tid & 31;
    int n2 = n0 + nt2 * 4;
    float4 s = *(const float4*)(bias + n2);
    #pragma unroll
    for (int k2 = 0; k2 < 8; k2++){
        float4 p = red[(k2*8 + bi2)*32 + nt2];
        s.x += p.x; s.y += p.y; s.z += p.z; s.w += p.w;
    }
    *(float4*)(ws + OFF_G + (size_t)(b0 + bi2)*NG + n2) = s;
}

// ---- fused launches: gates blocks first (overlap under attention BW phase) ----
__global__ __launch_bounds__(256, 4) void fused0_k(const float* __restrict__ hid,
                                                   const float* __restrict__ batch,
                                                   const float* __restrict__ h0,
                                                   const float* __restrict__ s0,
                                                   const float* __restrict__ Wih,
                                                   const float* __restrict__ Whh,
                                                   const float* __restrict__ bias,
                                                   float* __restrict__ ws){
    __shared__ float smem[8192];
    if (blockIdx.x < GB){ gates_body(Wih, Whh, bias, batch, h0, ws, smem, blockIdx.x); return; }
    int bid = blockIdx.x - GB;
    int b = bid >> 4, chunk = bid & (S - 1);
    // ||s0||^2 computed per-block (no init kernel)
    float ssq = 0.f;
    int t = threadIdx.x;
    {
        float v0 = s0[(size_t)b*H + t];
        float v1 = s0[(size_t)b*H + 256 + t];
        ssq = v0*v0 + v1*v1;
    }
    float rssb = rsqrtf(block_sum256s(ssq, smem + 2052));
    float* pl = ws + OFF_PL + b*S + chunk;
    float* pc = ws + OFF_PCTX + ((size_t)(b*S + chunk))*H;
    attn_first_body(hid, s0 + (size_t)b*H, rssb, ws, smem, pl, pc, b, chunk);
}

__global__ __launch_bounds__(256, 4) void fusedN_k(const float* __restrict__ Wih,
                                                   const float* __restrict__ Whh,
                                                   const float* __restrict__ bias,
                                                   float* __restrict__ ws){
    __shared__ float smem[8192];
    if (blockIdx.x < GB){ gates_body(Wih, Whh, bias, ws + OFF_X, ws + OFF_H, ws, smem, blockIdx.x); return; }
    int bid = blockIdx.x - GB;
    int b = bid >> 4, chunk = bid & (S - 1);
    float rssb = rsqrtf(ws[OFF_SS + b]);
    float* pl = ws + OFF_PL + b*S + chunk;
    float* pc = ws + OFF_PCTX + ((size_t)(b*S + chunk))*H;
    attn_steady_body(ws + OFF_S + (size_t)b*H, rssb, ws, smem, pl, pc, b, chunk);
}

// ---- fused tail: combine + LSTM cell + MLP head + scatter; 512 threads ----
__global__ __launch_bounds__(512) void tail_k(const float* __restrict__ W1, const float* __restrict__ b1,
                                              const float* __restrict__ W2, const float* __restrict__ b2,
                                              const float* __restrict__ sprev,
                                              float* __restrict__ ws, float* __restrict__ out, int st){
    int b = blockIdx.x, t = threadIdx.x;
    __shared__ float hl[512];
    __shared__ float part[8][64];
    __shared__ float t1[64];
    __shared__ float rr[8];

    float Ls = 0.f;
    #pragma unroll
    for (int i = 0; i < S; i++) Ls += ws[OFF_PL + b*S + i];
    float inv = 1.0f / Ls;

    float cx = 0.f;
    #pragma unroll
    for (int i = 0; i < S; i++) cx += ws[OFF_PCTX + ((size_t)b*S + i)*H + t];
    const float* g = ws + OFF_G + (size_t)b * NG;
    float sn = sprev[(size_t)b*H + t] + cx * inv;
    float gi = g[t], gf = g[512 + t], gg = g[1024 + t], go = g[1536 + t];
    float c  = sigf(gf) * sn + sigf(gi) * tanhf(gg);
    float hv = sigf(go) * tanhf(c);
    ws[OFF_S + (size_t)b*H + t] = c;
    ws[OFF_H + (size_t)b*H + t] = hv;
    hl[t] = hv;
    float csq = c * c;
    for (int off = 32; off; off >>= 1) csq += __shfl_xor(csq, off, 64);
    int wv = t >> 6, ln = t & 63;
    if (ln == 0) rr[wv] = csq;
    __syncthreads();
    if (t == 0){
        float s = 0.f;
        #pragma unroll
        for (int i = 0; i < 8; i++) s += rr[i];
        ws[OFF_SS + b] = s;
    }

    // MLP layer 1: 8-way k-split x 64 outputs
    int j = t & 63, q = t >> 6;
    float a = 0.f;
    #pragma unroll 4
    for (int k = q*64; k < q*64 + 64; k++) a += hl[k] * W1[k*64 + j];
    part[q][j] = a;
    __syncthreads();
    if (t < 64){
        float v = b1[t];
        #pragma unroll
        for (int i = 0; i < 8; i++) v += part[i][t];
        t1[t] = v > 0.f ? v : 0.01f * v;
    }
    __syncthreads();
    // MLP layer 2: one output per thread
    float a2 = b2[t];
    #pragma unroll
    for (int k = 0; k < 64; k++) a2 += t1[k] * W2[k*512 + t];
    ws[OFF_X + (size_t)b*D + t] = a2;
    int idx = st * D + t;
    out[(size_t)b * (D*T) + (size_t)(idx % T) * D + (idx / T)] = a2;
}

extern "C" void kernel_launch(void* const* d_in, const int* in_sizes, int n_in,
                              void* d_out, int out_size, void* d_ws, size_t ws_size,
                              hipStream_t stream) {
    const float* batch = (const float*)d_in[0];
    const float* hid   = (const float*)d_in[1];
    const float* h0    = (const float*)d_in[2];
    const float* s0    = (const float*)d_in[3];
    const float* Wih   = (const float*)d_in[4];
    const float* Whh   = (const float*)d_in[5];
    const float* bl    = (const float*)d_in[6];
    const float* W1    = (const float*)d_in[7];
    const float* b1    = (const float*)d_in[8];
    const float* W2    = (const float*)d_in[9];
    const float* b2    = (const float*)d_in[10];
    float* out = (float*)d_out;
    float* ws  = (float*)d_ws;

    fused0_k<<<B*S + GB, 256, 0, stream>>>(hid, batch, h0, s0, Wih, Whh, bl, ws);
    tail_k<<<B, 512, 0, stream>>>(W1, b1, W2, b2, s0, ws, out, 0);
    for (int st = 1; st < T; st++){
        fusedN_k<<<B*S + GB, 256, 0, stream>>>(Wih, Whh, bl, ws);
        tail_k<<<B, 512, 0, stream>>>(W1, b1, W2, b2, ws + OFF_S, ws, out, st);
    }
}

// Round 6
// 1354.960 us; speedup vs baseline: 2.5624x; 2.5624x over previous
//
#include <hip/hip_runtime.h>
#include <math.h>

#define B 128
#define L 2048
#define H 512
#define D 512
#define NG 2048   // 4*H
#define T 10
#define S 16      // L-chunks per batch row for attention partials
#define GB 256    // gates blocks fused in front of attention blocks

// workspace layout (float offsets); ws_size = 2 GiB
#define OFF_S    ((size_t)0)        // c state (attention query), B*H
#define OFF_H    ((size_t)65536)    // hidden h, B*H
#define OFF_X    ((size_t)131072)   // current x, B*D
#define OFF_SS   ((size_t)196608)   // ||s||^2 per b, B
#define OFF_G    ((size_t)196736)   // gates, B*NG
#define OFF_PL   ((size_t)460928)   // partial l, B*S
#define OFF_PCTX ((size_t)462976)   // partial ctx, B*S*H
#define OFF_RN   ((size_t)1511552)  // 1/||h_l||, B*L
#define OFF_HB   ((size_t)1773696)  // bf16 copy of hid_states (row-major), B*L*H bf16

__device__ __forceinline__ float sigf(float x){ return 1.0f / (1.0f + __expf(-x)); }

__device__ __forceinline__ unsigned int b16r(float f){   // fp32 -> bf16 bits, RNE
    unsigned int u = __float_as_uint(f);
    return (u + 0x7FFFu + ((u >> 16) & 1u)) >> 16;
}
__device__ __forceinline__ unsigned int pack2(float lo, float hi){
    return b16r(lo) | (b16r(hi) << 16);
}

#define UNPK(u, f0, f1) { f0 = __uint_as_float((u) << 16); f1 = __uint_as_float((u) & 0xFFFF0000u); }

__device__ __forceinline__ float block_sum256(float v){
    for (int off = 32; off; off >>= 1) v += __shfl_xor(v, off, 64);
    __shared__ float r[4];
    int wave = threadIdx.x >> 6, lane = threadIdx.x & 63;
    if (lane == 0) r[wave] = v;
    __syncthreads();
    return r[0] + r[1] + r[2] + r[3];
}

// full 64-lane reduce
__device__ __forceinline__ float red64(float v){
    v += __shfl_xor(v, 1, 64);
    v += __shfl_xor(v, 2, 64);
    v += __shfl_xor(v, 4, 64);
    v += __shfl_xor(v, 8, 64);
    v += __shfl_xor(v, 16, 64);
    v += __shfl_xor(v, 32, 64);
    return v;
}

// ---- init: s=s0, h=h0, x=batch, ss=||s0||^2 ----
__global__ void init_k(const float* __restrict__ s0, const float* __restrict__ h0,
                       const float* __restrict__ x0, float* __restrict__ ws){
    int b = blockIdx.x, t = threadIdx.x;
    float ssq = 0.f;
    for (int h = t; h < H; h += 256){
        float sv = s0[b*H + h];
        ws[OFF_S + b*H + h] = sv;
        ws[OFF_H + b*H + h] = h0[b*H + h];
        ssq += sv * sv;
    }
    for (int d = t; d < D; d += 256) ws[OFF_X + b*D + d] = x0[b*D + d];
    float tot = block_sum256(ssq);
    if (t == 0) ws[OFF_SS + b] = tot;
}

// ---- load s slice (pre-scaled by 1/||s||): elems lane*8 .. +7 ----
__device__ __forceinline__ void load_snorm8(const float* __restrict__ ws, int b, int lane, float* sf){
    const float* sb = ws + OFF_S + (size_t)b * H + lane * 8;
    float rssb = rsqrtf(ws[OFF_SS + b]);
    float4 a = *(const float4*)sb;
    float4 c = *(const float4*)(sb + 4);
    sf[0]=a.x*rssb; sf[1]=a.y*rssb; sf[2]=a.z*rssb; sf[3]=a.w*rssb;
    sf[4]=c.x*rssb; sf[5]=c.y*rssb; sf[6]=c.z*rssb; sf[7]=c.w*rssb;
}

// ---- epilogue: lanes own disjoint elem slices -> no intra-wave combine; cross-wave via LDS ----
__device__ __forceinline__ void attn_epilogue64(float* ctx, float lsum, float* smem,
                                                float* __restrict__ ws, int b, int chunk,
                                                int wave, int lane){
    float (*lctx)[512] = (float(*)[512])smem;   // 4*512 floats
    float* ll = smem + 2048;                    // 4 floats
    {
        float4 v0 = { ctx[0], ctx[1], ctx[2], ctx[3] };
        float4 v1 = { ctx[4], ctx[5], ctx[6], ctx[7] };
        *(float4*)&lctx[wave][lane*8]     = v0;
        *(float4*)&lctx[wave][lane*8 + 4] = v1;
        if (lane == 0) ll[wave] = lsum;
    }
    __syncthreads();
    int t = threadIdx.x;
    float* pc = ws + OFF_PCTX + ((size_t)b * S + chunk) * H;
    pc[t]       = lctx[0][t]     + lctx[1][t]     + lctx[2][t]     + lctx[3][t];
    pc[t + 256] = lctx[0][t+256] + lctx[1][t+256] + lctx[2][t+256] + lctx[3][t+256];
    if (t == 0) ws[OFF_PL + b*S + chunk] = ll[0] + ll[1] + ll[2] + ll[3];
}

// ---- step-0 attention: reads fp32 hid, emits row-major bf16 copy + rn ----
// 64 lanes x 8 elems; 1 row per iter, 32 iters per wave
__device__ __forceinline__ void attn_first_body(const float* __restrict__ hid,
                                                float* __restrict__ ws, int bid, float* smem){
    int b = bid >> 4, chunk = bid & (S - 1);
    int wave = threadIdx.x >> 6, lane = threadIdx.x & 63;
    float sf[8];
    load_snorm8(ws, b, lane, sf);

    int l0w = chunk * 128 + wave * 32;
    const float* hsrc = hid + ((size_t)b * L + l0w) * H + lane * 8;
    uint4* hbw = (uint4*)(ws + OFF_HB) + ((size_t)b * L + l0w) * 64 + lane;
    float* rnw = ws + OFF_RN + (size_t)b * L + l0w;

    float ctx[8];
    #pragma unroll
    for (int k = 0; k < 8; k++) ctx[k] = 0.f;
    float lsum = 0.f;

    for (int it = 0; it < 32; it++){
        const float* src = hsrc + (size_t)it * H;
        float4 a = *(const float4*)src;
        float4 c = *(const float4*)(src + 4);
        float f[8];
        f[0]=a.x; f[1]=a.y; f[2]=a.z; f[3]=a.w;
        f[4]=c.x; f[5]=c.y; f[6]=c.z; f[7]=c.w;

        float sq = 0.f, dot = 0.f;
        #pragma unroll
        for (int k = 0; k < 8; k++){ sq += f[k]*f[k]; dot += f[k]*sf[k]; }
        sq  = red64(sq);
        dot = red64(dot);
        float rnv = rsqrtf(sq);
        if (lane == 0) rnw[it] = rnv;

        uint4 o;
        o.x = pack2(f[0], f[1]);
        o.y = pack2(f[2], f[3]);
        o.z = pack2(f[4], f[5]);
        o.w = pack2(f[6], f[7]);
        hbw[(size_t)it * 64] = o;

        float p = __expf(dot * rnv);   // cosine score in [-1,1] -> no max needed
        lsum += p;
        #pragma unroll
        for (int k = 0; k < 8; k++) ctx[k] += p * f[k];
    }
    attn_epilogue64(ctx, lsum, smem, ws, b, chunk, wave, lane);
}

// ---- steady-state attention on row-major bf16 copy; same 64x8 tiling ----
__device__ __forceinline__ void attn_steady_body(float* __restrict__ ws, int bid, float* smem){
    int b = bid >> 4, chunk = bid & (S - 1);
    int wave = threadIdx.x >> 6, lane = threadIdx.x & 63;
    float sf[8];
    load_snorm8(ws, b, lane, sf);

    int l0w = chunk * 128 + wave * 32;
    const uint4* hbu = (const uint4*)(ws + OFF_HB) + ((size_t)b * L + l0w) * 64 + lane;
    const float* rnp = ws + OFF_RN + (size_t)b * L + l0w;

    float ctx[8];
    #pragma unroll
    for (int k = 0; k < 8; k++) ctx[k] = 0.f;
    float lsum = 0.f;

    for (int it = 0; it < 32; it++){
        uint4 u = hbu[(size_t)it * 64];
        float rnv = rnp[it];
        float f[8];
        UNPK(u.x, f[0], f[1])
        UNPK(u.y, f[2], f[3])
        UNPK(u.z, f[4], f[5])
        UNPK(u.w, f[6], f[7])

        float dot = 0.f;
        #pragma unroll
        for (int k = 0; k < 8; k++) dot += f[k] * sf[k];
        dot = red64(dot);
        float p = __expf(dot * rnv);
        lsum += p;
        #pragma unroll
        for (int k = 0; k < 8; k++) ctx[k] += p * f[k];
    }
    attn_epilogue64(ctx, lsum, smem, ws, b, chunk, wave, lane);
}

// ---- gates = x @ W_ih + h @ W_hh + b ; outer-product, each weight read ONCE per block ----
__device__ __forceinline__ void gates_body(const float* __restrict__ Wih,
                                           const float* __restrict__ Whh,
                                           const float* __restrict__ bias,
                                           float* __restrict__ ws,
                                           float* smem, int gid){
    int tid = threadIdx.x;
    int b0 = (gid >> 4) * 8, n0 = (gid & 15) * 128;
    float* xs  = smem;          // [8][512]
    float* hsm = smem + 4096;   // [8][512]
    {
        int r = tid >> 5, c = (tid & 31) * 16;
        const float* xsrc = ws + OFF_X + (size_t)(b0 + r) * D + c;
        const float* hsrc = ws + OFF_H + (size_t)(b0 + r) * H + c;
        #pragma unroll
        for (int j = 0; j < 4; j++){
            *(float4*)&xs[r*512 + c + j*4]  = *(const float4*)(xsrc + j*4);
            *(float4*)&hsm[r*512 + c + j*4] = *(const float4*)(hsrc + j*4);
        }
    }
    __syncthreads();
    int nt = tid & 31, kh = tid >> 5;
    int n = n0 + nt * 4;
    float4 acc[8];
    #pragma unroll
    for (int bi = 0; bi < 8; bi++){ acc[bi].x = 0.f; acc[bi].y = 0.f; acc[bi].z = 0.f; acc[bi].w = 0.f; }
    const float* w1p = Wih + (size_t)(kh * 64) * NG + n;
    const float* w2p = Whh + (size_t)(kh * 64) * NG + n;
    const float* xk = xs  + kh * 64;
    const float* hk = hsm + kh * 64;
    #pragma unroll 2
    for (int k = 0; k < 64; k++){
        float4 w1 = *(const float4*)(w1p + (size_t)k * NG);
        float4 w2 = *(const float4*)(w2p + (size_t)k * NG);
        #pragma unroll
        for (int bi = 0; bi < 8; bi++){
            float xv = xk[bi*512 + k], hv = hk[bi*512 + k];
            acc[bi].x += xv*w1.x + hv*w2.x;
            acc[bi].y += xv*w1.y + hv*w2.y;
            acc[bi].z += xv*w1.z + hv*w2.z;
            acc[bi].w += xv*w1.w + hv*w2.w;
        }
    }
    __syncthreads();                         // all LDS reads done before realias
    float4* red = (float4*)smem;             // [8 kh][8 bi][32 nt] = 8192 floats
    #pragma unroll
    for (int bi = 0; bi < 8; bi++) red[(kh*8 + bi)*32 + nt] = acc[bi];
    __syncthreads();
    int bi2 = tid >> 5, nt2 = tid & 31;
    int n2 = n0 + nt2 * 4;
    float4 s = *(const float4*)(bias + n2);
    #pragma unroll
    for (int k2 = 0; k2 < 8; k2++){
        float4 p = red[(k2*8 + bi2)*32 + nt2];
        s.x += p.x; s.y += p.y; s.z += p.z; s.w += p.w;
    }
    *(float4*)(ws + OFF_G + (size_t)(b0 + bi2)*NG + n2) = s;
}

// ---- fused launches: gates blocks first (overlap under attention BW phase) ----
__global__ __launch_bounds__(256) void fused0_k(const float* __restrict__ hid,
                                                const float* __restrict__ Wih,
                                                const float* __restrict__ Whh,
                                                const float* __restrict__ bias,
                                                float* __restrict__ ws){
    __shared__ float smem[8192];
    if (blockIdx.x < GB){ gates_body(Wih, Whh, bias, ws, smem, blockIdx.x); return; }
    attn_first_body(hid, ws, blockIdx.x - GB, smem);
}

__global__ __launch_bounds__(256) void fusedN_k(const float* __restrict__ Wih,
                                                const float* __restrict__ Whh,
                                                const float* __restrict__ bias,
                                                float* __restrict__ ws){
    __shared__ float smem[8192];
    if (blockIdx.x < GB){ gates_body(Wih, Whh, bias, ws, smem, blockIdx.x); return; }
    attn_steady_body(ws, blockIdx.x - GB, smem);
}

// ---- fused tail: combine + LSTM cell + MLP head + scatter; 512 threads ----
__global__ __launch_bounds__(512) void tail_k(const float* __restrict__ W1, const float* __restrict__ b1,
                                              const float* __restrict__ W2, const float* __restrict__ b2,
                                              float* __restrict__ ws, float* __restrict__ out, int st){
    int b = blockIdx.x, t = threadIdx.x;
    __shared__ float hl[512];
    __shared__ float part[8][64];
    __shared__ float t1[64];
    __shared__ float rr[8];

    float Ls = 0.f;
    #pragma unroll
    for (int i = 0; i < S; i++) Ls += ws[OFF_PL + b*S + i];
    float inv = 1.0f / Ls;

    float cx = 0.f;
    #pragma unroll
    for (int i = 0; i < S; i++) cx += ws[OFF_PCTX + ((size_t)b*S + i)*H + t];
    const float* g = ws + OFF_G + (size_t)b * NG;
    float sn = ws[OFF_S + b*H + t] + cx * inv;
    float gi = g[t], gf = g[512 + t], gg = g[1024 + t], go = g[1536 + t];
    float c  = sigf(gf) * sn + sigf(gi) * tanhf(gg);
    float hv = sigf(go) * tanhf(c);
    ws[OFF_S + b*H + t] = c;
    ws[OFF_H + b*H + t] = hv;
    hl[t] = hv;
    float csq = c * c;
    for (int off = 32; off; off >>= 1) csq += __shfl_xor(csq, off, 64);
    int wv = t >> 6, ln = t & 63;
    if (ln == 0) rr[wv] = csq;
    __syncthreads();
    if (t == 0){
        float s = 0.f;
        #pragma unroll
        for (int i = 0; i < 8; i++) s += rr[i];
        ws[OFF_SS + b] = s;
    }

    // MLP layer 1: 8-way k-split x 64 outputs
    int j = t & 63, q = t >> 6;
    float a = 0.f;
    #pragma unroll 4
    for (int k = q*64; k < q*64 + 64; k++) a += hl[k] * W1[k*64 + j];
    part[q][j] = a;
    __syncthreads();
    if (t < 64){
        float v = b1[t];
        #pragma unroll
        for (int i = 0; i < 8; i++) v += part[i][t];
        t1[t] = v > 0.f ? v : 0.01f * v;
    }
    __syncthreads();
    // MLP layer 2: one output per thread
    float a2 = b2[t];
    #pragma unroll
    for (int k = 0; k < 64; k++) a2 += t1[k] * W2[k*512 + t];
    ws[OFF_X + (size_t)b*D + t] = a2;
    int idx = st * D + t;
    out[(size_t)b * (D*T) + (size_t)(idx % T) * D + (idx / T)] = a2;
}

extern "C" void kernel_launch(void* const* d_in, const int* in_sizes, int n_in,
                              void* d_out, int out_size, void* d_ws, size_t ws_size,
                              hipStream_t stream) {
    const float* batch = (const float*)d_in[0];
    const float* hid   = (const float*)d_in[1];
    const float* h0    = (const float*)d_in[2];
    const float* s0    = (const float*)d_in[3];
    const float* Wih   = (const float*)d_in[4];
    const float* Whh   = (const float*)d_in[5];
    const float* bl    = (const float*)d_in[6];
    const float* W1    = (const float*)d_in[7];
    const float* b1    = (const float*)d_in[8];
    const float* W2    = (const float*)d_in[9];
    const float* b2    = (const float*)d_in[10];
    float* out = (float*)d_out;
    float* ws  = (float*)d_ws;

    init_k<<<B, 256, 0, stream>>>(s0, h0, batch, ws);
    fused0_k<<<B*S + GB, 256, 0, stream>>>(hid, Wih, Whh, bl, ws);
    tail_k<<<B, 512, 0, stream>>>(W1, b1, W2, b2, ws, out, 0);
    for (int st = 1; st < T; st++){
        fusedN_k<<<B*S + GB, 256, 0, stream>>>(Wih, Whh, bl, ws);
        tail_k<<<B, 512, 0, stream>>>(W1, b1, W2, b2, ws, out, st);
    }
}